// Round 5
// baseline (409.891 us; speedup 1.0000x reference)
//
#include <hip/hip_runtime.h>
#include <math.h>

#define NB 16
#define TT 800
#define FF 90
#define SS 128
#define LL 200
#define NEGV (-1e30f)
#define XB (16 * FF)   // 1440 floats per emission batch

// blocks 0..15: denominator FSA — linear-domain scaled GEMV, pair-split dests,
//               wave-local reduction, double-buffered V, ONE barrier/step.
// blocks 16..19: numerator chain, one wave per utterance, barrier-free.
__global__ __launch_bounds__(256) void mmi_forward(
    const float* __restrict__ x,          // N*T*F log-softmax
    const int*   __restrict__ sup,        // N*3
    const float* __restrict__ trans,      // S*S
    const int*   __restrict__ den_labels, // S
    const int*   __restrict__ num_labels, // N*L
    const int*   __restrict__ num_lens,   // N
    float*       __restrict__ ws)
{
    const int tid = threadIdx.x;

    if (blockIdx.x < NB) {
        // ---------------- denominator ----------------
        __shared__ __align__(16) float sh_v[2][SS];  // ping-pong scaled alphas
        __shared__ float sh_red[4];
        __shared__ __align__(16) float xbuf[2][XB];  // raw x rows, 16-frame batches

        const int n  = blockIdx.x;
        const int nf = sup[n * 3 + 2];
        const int w  = tid >> 6, l = tid & 63;
        const int d  = w * 32 + (l >> 1);   // owned dest state
        const int c  = l & 1;               // source half: 64c..64c+63

        // E fragment: E[64c+j][d], j=0..63 (64 VGPRs)
        float e[64];
        #pragma unroll
        for (int j = 0; j < 64; ++j)
            e[j] = __expf(trans[(size_t)(64 * c + j) * SS + d]);

        const int lab = den_labels[d];
        const float* xb = x + (size_t)n * TT * FF;

        // stage batch 0 into xbuf[0]
        {
            const float4* s0 = (const float4*)xb;
            float4 p0 = s0[tid];
            float4 p1; if (tid < 104) p1 = s0[256 + tid];
            float4* d0 = (float4*)xbuf[0];
            d0[tid] = p0;
            if (tid < 104) d0[256 + tid] = p1;
        }
        if (tid < SS) sh_v[0][tid] = (tid == 0) ? 1.0f : 0.0f;
        float logM = 0.0f, v = 0.0f;
        float4 pf0, pf1;
        __syncthreads();

        for (int t = 0; t < nf; ++t) {
            const int b = t >> 4;
            // emission for owned dest (independent: issues early)
            const float pe = __expf(xbuf[b & 1][(t & 15) * FF + lab]);

            // GEMV half-dot: p = sum_j V[64c+j] * E[64c+j][d]
            const float4* av = (const float4*)(sh_v[t & 1] + 64 * c);
            float a0 = 0.f, a1 = 0.f, a2 = 0.f, a3 = 0.f;
            #pragma unroll
            for (int j = 0; j < 16; ++j) {
                const float4 s4 = av[j];
                a0 = fmaf(s4.x, e[4 * j + 0], a0);
                a1 = fmaf(s4.y, e[4 * j + 1], a1);
                a2 = fmaf(s4.z, e[4 * j + 2], a2);
                a3 = fmaf(s4.w, e[4 * j + 3], a3);
            }
            float p = (a0 + a1) + (a2 + a3);
            p += __shfl_xor(p, 1, 64);   // combine the two source halves
            v = p * pe;

            // mid-batch global prefetch of next emission batch
            if ((t & 15) == 8) {
                const int tn = (b + 1) * 16;
                if (tn < nf) {
                    const float4* s = (const float4*)(xb + (size_t)tn * FF);
                    pf0 = s[tid];
                    if (tid < 104) pf1 = s[256 + tid];
                }
            }

            const bool rs = ((t & 15) == 15);
            if (rs) {
                // block max via wave reduce (each wave covers 32 dests, duplicated)
                float m = v;
                #pragma unroll
                for (int off = 32; off >= 1; off >>= 1)
                    m = fmaxf(m, __shfl_xor(m, off, 64));
                if (l == 0) sh_red[w] = m;
                // commit prefetched batch
                const int tn = (b + 1) * 16;
                if (tn < nf) {
                    float4* dst = (float4*)xbuf[(b + 1) & 1];
                    dst[tid] = pf0;
                    if (tid < 104) dst[256 + tid] = pf1;
                }
                __syncthreads();
                const float mm = fmaxf(fmaxf(fmaxf(sh_red[0], sh_red[1]),
                                             fmaxf(sh_red[2], sh_red[3])), 1e-37f);
                v *= (1.0f / mm);
                logM += __logf(mm);
            }
            if (c == 0) sh_v[(t + 1) & 1][d] = v;
            __syncthreads();   // V(t+1) visible; V(t) reads retired
        }

        // den score = logM + log(sum_d v[d])
        {
            float ssum = (c == 0) ? v : 0.0f;
            #pragma unroll
            for (int off = 32; off >= 1; off >>= 1)
                ssum += __shfl_xor(ssum, off, 64);
            if (l == 0) sh_red[w] = ssum;
        }
        __syncthreads();
        if (tid == 0)
            ws[n] = logM + __logf(sh_red[0] + sh_red[1] + sh_red[2] + sh_red[3]);
    } else {
        // ------------- numerator: one wave per utt, no barriers -------------
        const int w = tid >> 6, l = tid & 63;
        const int n = (blockIdx.x - NB) * 4 + w;
        const int nf = sup[n * 3 + 2];
        const float* xb = x + (size_t)n * TT * FF;
        const int* nl = num_labels + n * LL;

        int li[4];
        #pragma unroll
        for (int k = 0; k < 4; ++k) li[k] = nl[min(4 * l + k, LL - 1)];

        float a4[4] = {NEGV, NEGV, NEGV, NEGV};  // states 4l+1..4l+4
        float ea[4], eb[4];
        #pragma unroll
        for (int k = 0; k < 4; ++k) ea[k] = xb[li[k]];
        {
            const float* xr = xb + (size_t)min(1, nf - 1) * FF;
            #pragma unroll
            for (int k = 0; k < 4; ++k) eb[k] = xr[li[k]];
        }

        auto step = [&](float (&ee)[4], int t) {
            float left = __shfl_up(a4[3], 1, 64);
            if (l == 0) left = (t == 0) ? 0.0f : NEGV;
            float prev = left;
            #pragma unroll
            for (int k = 0; k < 4; ++k) {
                const float a = a4[k], b = prev;
                const float mx = fmaxf(a, b), mn = fminf(a, b);
                const float nv = mx + __logf(1.0f + __expf(mn - mx)) + ee[k];
                prev = a4[k];
                a4[k] = nv;
            }
            const int t2 = min(t + 2, nf - 1);
            const float* xr = xb + (size_t)t2 * FF;
            #pragma unroll
            for (int k = 0; k < 4; ++k) ee[k] = xr[li[k]];
        };

        int t = 0;
        while (t < nf) {
            step(ea, t); ++t;
            if (t >= nf) break;
            step(eb, t); ++t;
        }

        const int idx = num_lens[n] - 1;   // alpha position num_lens = state idx+1
        if ((idx >> 2) == l) {
            const int kk = idx & 3;
            float vv = (kk == 0) ? a4[0] : (kk == 1) ? a4[1] : (kk == 2) ? a4[2] : a4[3];
            ws[NB + n] = vv;
        }
    }
}

__global__ void mmi_finalize(const float* __restrict__ ws,
                             const int* __restrict__ sup,
                             float* __restrict__ out)
{
    const int tid = threadIdx.x;  // 64 threads
    float tot_score = 0.0f, tot_frames = 0.0f, all_frames = 0.0f;
    if (tid < NB) {
        const float tot = ws[NB + tid] - ws[tid];   // num - den (DEN_SCALE=1)
        const int nf = sup[tid * 3 + 2];
        const bool fin = isfinite(tot) && (tot > 0.5f * NEGV);
        tot_score  = fin ? tot : 0.0f;
        tot_frames = fin ? (float)nf : 0.0f;
        all_frames = (float)nf;
    }
    #pragma unroll
    for (int off = 32; off >= 1; off >>= 1) {
        tot_score  += __shfl_xor(tot_score, off, 64);
        tot_frames += __shfl_xor(tot_frames, off, 64);
        all_frames += __shfl_xor(all_frames, off, 64);
    }
    if (tid == 0) {
        out[0] = tot_score;
        out[1] = tot_frames;
        out[2] = all_frames;
    }
}

extern "C" void kernel_launch(void* const* d_in, const int* in_sizes, int n_in,
                              void* d_out, int out_size, void* d_ws, size_t ws_size,
                              hipStream_t stream) {
    const float* x          = (const float*)d_in[0];
    const int*   sup        = (const int*)d_in[1];
    const float* trans      = (const float*)d_in[2];
    const int*   den_labels = (const int*)d_in[3];
    const int*   num_labels = (const int*)d_in[4];
    const int*   num_lens   = (const int*)d_in[5];
    float* ws  = (float*)d_ws;
    float* out = (float*)d_out;

    mmi_forward<<<dim3(20), dim3(256), 0, stream>>>(
        x, sup, trans, den_labels, num_labels, num_lens, ws);
    mmi_finalize<<<dim3(1), dim3(64), 0, stream>>>(ws, sup, out);
}

// Round 6
// 326.376 us; speedup vs baseline: 1.2559x; 1.2559x over previous
//
#include <hip/hip_runtime.h>
#include <math.h>

#define NB 16
#define TT 800
#define FF 90
#define SS 128
#define LL 200
#define NEGV (-1e30f)

#define NODES 25     // nodes per utterance
#define NDRX 32      // frames per node
#define XSTR 68      // X row stride in u32 words (136 bf16: +8 pad kills bank alias)
#define LN2F 0.69314718055994531f

typedef __attribute__((ext_vector_type(8))) short short8;
typedef __attribute__((ext_vector_type(4))) float float4v;

static __device__ __forceinline__ unsigned short f2bf(float x) {
    union { float f; unsigned u; } v; v.f = x;
    unsigned r = (v.u + 0x7FFFu + ((v.u >> 16) & 1u)) >> 16;
    return (unsigned short)r;
}

// ======================= Kernel A: node products + numerator =================
// blocks [0, 16*NODES): block b computes P_{u,i} = prod_{t=t0}^{t0+31} E diag(p_t)
//   (bf16, rescaled by 2^-eacc; identity for t >= nf), u=b/NODES, i=b%NODES.
// blocks [16*NODES, 16*NODES+4): numerator chain, one wave per utterance.
__global__ __launch_bounds__(256) void mmi_nodes(
    const float* __restrict__ x,
    const int*   __restrict__ sup,
    const float* __restrict__ trans,
    const int*   __restrict__ den_labels,
    const int*   __restrict__ num_labels,
    const int*   __restrict__ num_lens,
    unsigned*    __restrict__ Pout,     // [16*NODES][8192] u32 (bf16 pairs)
    float*       __restrict__ scales,   // [16*NODES] pow2 exponent counts
    float*       __restrict__ nsc)      // [16] numerator scores
{
    const int tid = threadIdx.x;

    if (blockIdx.x < NB * NODES) {
        __shared__ unsigned Xs[128 * XSTR];     // running product, bf16 pairs
        __shared__ float ptab[NDRX * SS];       // emission exps for 32 frames
        __shared__ float sh_red[4];

        const int u  = blockIdx.x / NODES;
        const int nd = blockIdx.x % NODES;
        const int t0 = nd * NDRX;
        const int nf = sup[u * 3 + 2];
        unsigned* Pg = Pout + (size_t)(u * NODES + nd) * 8192;

        if (t0 >= nf) {   // whole node frozen -> identity matrix
            #pragma unroll
            for (int k2 = 0; k2 < 32; ++k2) {
                const int ww = tid + k2 * 256;
                const int row = ww >> 6, colw = ww & 63;
                unsigned val = 0;
                if (row == 2 * colw)     val |= 0x3F80u;
                if (row == 2 * colw + 1) val |= 0x3F800000u;
                Pg[ww] = val;
            }
            if (tid == 0) scales[u * NODES + nd] = 0.0f;
            return;
        }

        const int w = tid >> 6, l = tid & 63;
        const int m15 = l & 15, q = l >> 4;

        // B-fragments of E=exp(trans): B[k=ch*32+q*8+j][col=32w+16ct+m15]
        short8 bfrag[2][4];
        #pragma unroll
        for (int ct = 0; ct < 2; ++ct) {
            const int col = 32 * w + 16 * ct + m15;
            #pragma unroll
            for (int ch = 0; ch < 4; ++ch) {
                short8 f;
                #pragma unroll
                for (int j = 0; j < 8; ++j)
                    f[j] = (short)f2bf(__expf(trans[(ch * 32 + q * 8 + j) * SS + col]));
                bfrag[ct][ch] = f;
            }
        }

        // emission table: ptab[t][d] = exp(x[u][t0+t][lab[d]])
        for (int idx = tid; idx < NDRX * SS; idx += 256) {
            const int tt = idx >> 7, d = idx & 127;
            ptab[idx] = __expf(x[((size_t)u * TT + (t0 + tt)) * FF + den_labels[d]]);
        }
        __syncthreads();

        // X init = E * diag(p_0)
        #pragma unroll
        for (int k2 = 0; k2 < 32; ++k2) {
            const int ww = tid + k2 * 256;
            const int row = ww >> 6, colw = ww & 63;
            const float2 t2 = ((const float2*)trans)[ww];
            const float p0 = ptab[2 * colw], p1 = ptab[2 * colw + 1];
            Xs[row * XSTR + colw] = (unsigned)f2bf(__expf(t2.x) * p0)
                                  | ((unsigned)f2bf(__expf(t2.y) * p1) << 16);
        }
        if (tid < 4) sh_red[tid] = 1.0f;
        int eacc = 0;
        __syncthreads();

        const unsigned short* Xh = (const unsigned short*)Xs;
        const int kmax = min(NDRX, nf - t0);

        for (int k = 1; k < kmax; ++k) {
            // delayed exact pow2 scale from previous matmul's max
            const float mm = fmaxf(fmaxf(sh_red[0], sh_red[1]),
                                   fmaxf(sh_red[2], sh_red[3]));
            const int e = (int)((__float_as_uint(mm) >> 23) & 255u);
            const float sc = __uint_as_float((unsigned)(254 - e) << 23);
            eacc += (e - 127);

            // C = X * E   (64 MFMAs/wave)
            float4v acct[8][2];
            #pragma unroll
            for (int rt = 0; rt < 8; ++rt) {
                float4v z = {0.f, 0.f, 0.f, 0.f};
                acct[rt][0] = z; acct[rt][1] = z;
            }
            #pragma unroll
            for (int ch = 0; ch < 4; ++ch) {
                #pragma unroll
                for (int rt = 0; rt < 8; ++rt) {
                    const short8 af = *(const short8*)(Xh +
                        (16 * rt + m15) * (2 * XSTR) + ch * 32 + q * 8);
                    acct[rt][0] = __builtin_amdgcn_mfma_f32_16x16x32_bf16(
                        af, bfrag[0][ch], acct[rt][0], 0, 0, 0);
                    acct[rt][1] = __builtin_amdgcn_mfma_f32_16x16x32_bf16(
                        af, bfrag[1][ch], acct[rt][1], 0, 0, 0);
                }
            }

            // column scale by p_k, pow2 rescale, local max
            const float pc0 = ptab[k * SS + 32 * w + m15];
            const float pc1 = ptab[k * SS + 32 * w + 16 + m15];
            float vmax = 0.0f;
            #pragma unroll
            for (int rt = 0; rt < 8; ++rt)
                #pragma unroll
                for (int ct = 0; ct < 2; ++ct) {
                    const float pc = ct ? pc1 : pc0;
                    #pragma unroll
                    for (int r = 0; r < 4; ++r) {
                        const float val = acct[rt][ct][r] * pc * sc;
                        acct[rt][ct][r] = val;
                        vmax = fmaxf(vmax, val);
                    }
                }
            #pragma unroll
            for (int off = 32; off >= 1; off >>= 1)
                vmax = fmaxf(vmax, __shfl_xor(vmax, off, 64));

            __syncthreads();   // all A-fragment reads of X retired
            if (l == 0) sh_red[w] = vmax;

            // pack bf16 pairs (lanes l, l^1 hold cols c, c^1) and write X in place
            #pragma unroll
            for (int rt = 0; rt < 8; ++rt)
                #pragma unroll
                for (int ct = 0; ct < 2; ++ct)
                    #pragma unroll
                    for (int r = 0; r < 4; ++r) {
                        const float nbv = __shfl_xor(acct[rt][ct][r], 1, 64);
                        if (!(m15 & 1)) {
                            const int row = 16 * rt + 4 * q + r;
                            const int col = 32 * w + 16 * ct + m15;
                            Xs[row * XSTR + (col >> 1)] =
                                (unsigned)f2bf(acct[rt][ct][r])
                              | ((unsigned)f2bf(nbv) << 16);
                        }
                    }
            __syncthreads();   // new X + maxes visible
        }

        // write node product (strip padding) + scale
        #pragma unroll
        for (int k2 = 0; k2 < 32; ++k2) {
            const int ww = tid + k2 * 256;
            Pg[ww] = Xs[(ww >> 6) * XSTR + (ww & 63)];
        }
        if (tid == 0) scales[u * NODES + nd] = (float)eacc;
    } else {
        // ---------- numerator: one wave per utterance, barrier-free ----------
        const int w = tid >> 6, l = tid & 63;
        const int n = (blockIdx.x - NB * NODES) * 4 + w;
        const int nf = sup[n * 3 + 2];
        const float* xb = x + (size_t)n * TT * FF;
        const int* nl = num_labels + n * LL;

        int li[4];
        #pragma unroll
        for (int k = 0; k < 4; ++k) li[k] = nl[min(4 * l + k, LL - 1)];

        float a4[4] = {NEGV, NEGV, NEGV, NEGV};
        float ea[4], eb[4];
        #pragma unroll
        for (int k = 0; k < 4; ++k) ea[k] = xb[li[k]];
        {
            const float* xr = xb + (size_t)min(1, nf - 1) * FF;
            #pragma unroll
            for (int k = 0; k < 4; ++k) eb[k] = xr[li[k]];
        }

        auto step = [&](float (&ee)[4], int t) {
            float left = __shfl_up(a4[3], 1, 64);
            if (l == 0) left = (t == 0) ? 0.0f : NEGV;
            float prev = left;
            #pragma unroll
            for (int k = 0; k < 4; ++k) {
                const float a = a4[k], b = prev;
                const float mx = fmaxf(a, b), mn = fminf(a, b);
                const float nv = mx + __logf(1.0f + __expf(mn - mx)) + ee[k];
                prev = a4[k];
                a4[k] = nv;
            }
            const int t2 = min(t + 2, nf - 1);
            const float* xr = xb + (size_t)t2 * FF;
            #pragma unroll
            for (int k = 0; k < 4; ++k) ee[k] = xr[li[k]];
        };

        int t = 0;
        while (t < nf) {
            step(ea, t); ++t;
            if (t >= nf) break;
            step(eb, t); ++t;
        }

        const int idx = num_lens[n] - 1;
        if ((idx >> 2) == l) {
            const int kk = idx & 3;
            float vv = (kk == 0) ? a4[0] : (kk == 1) ? a4[1] : (kk == 2) ? a4[2] : a4[3];
            nsc[n] = vv;
        }
    }
}

// ======================= Kernel B: chain alpha through 25 nodes ==============
__global__ __launch_bounds__(256) void mmi_chain(
    const unsigned short* __restrict__ Pmat,   // [16][NODES][128*128] bf16
    const float* __restrict__ scales,          // [16*NODES]
    float* __restrict__ dsc)                   // [16] den scores
{
    __shared__ float sh_v[SS];
    __shared__ float sh_part[8 * SS];
    __shared__ float sh_red[2];

    const int u = blockIdx.x;
    const int tid = threadIdx.x;
    const int g = tid & 31, c = tid >> 5;
    const unsigned short* Pu = Pmat + (size_t)u * NODES * 16384;

    if (tid < SS) sh_v[tid] = (tid == 0) ? 1.0f : 0.0f;
    int   e2acc = 0;     // pow2 counts from alpha renorms
    float sscal = 0.0f;  // pow2 counts from node scales

    uint2 cur[16], nxt[16];
    #pragma unroll
    for (int j = 0; j < 16; ++j)
        cur[j] = *(const uint2*)(Pu + (16 * c + j) * SS + 4 * g);
    __syncthreads();

    for (int i = 0; i < NODES; ++i) {
        if (i + 1 < NODES) {
            const unsigned short* Pn = Pu + (size_t)(i + 1) * 16384;
            #pragma unroll
            for (int j = 0; j < 16; ++j)
                nxt[j] = *(const uint2*)(Pn + (16 * c + j) * SS + 4 * g);
        }
        sscal += scales[u * NODES + i];

        // partials: thread covers srcs 16c..16c+15 x dests 4g..4g+3
        const float4* av = (const float4*)(sh_v + 16 * c);
        float4 aa[4] = {av[0], av[1], av[2], av[3]};
        const float* as = (const float*)aa;
        float4 acc = make_float4(0.f, 0.f, 0.f, 0.f);
        #pragma unroll
        for (int j = 0; j < 16; ++j) {
            const float e0 = __uint_as_float(cur[j].x << 16);
            const float e1 = __uint_as_float(cur[j].x & 0xFFFF0000u);
            const float e2 = __uint_as_float(cur[j].y << 16);
            const float e3 = __uint_as_float(cur[j].y & 0xFFFF0000u);
            acc.x = fmaf(as[j], e0, acc.x);
            acc.y = fmaf(as[j], e1, acc.y);
            acc.z = fmaf(as[j], e2, acc.z);
            acc.w = fmaf(as[j], e3, acc.w);
        }
        *(float4*)(sh_part + c * SS + 4 * g) = acc;
        __syncthreads();

        float v = 0.0f;
        if (tid < SS) {
            float y = 0.0f;
            #pragma unroll
            for (int cc = 0; cc < 8; ++cc) y += sh_part[cc * SS + tid];
            v = y;
            float m = v;
            #pragma unroll
            for (int off = 32; off >= 1; off >>= 1)
                m = fmaxf(m, __shfl_xor(m, off, 64));
            if ((tid & 63) == 0) sh_red[tid >> 6] = m;
        }
        __syncthreads();
        if (tid < SS) {
            const float mm = fmaxf(fmaxf(sh_red[0], sh_red[1]), 1e-37f);
            const int e = (int)((__float_as_uint(mm) >> 23) & 255u);
            const float inv = __uint_as_float((unsigned)(254 - e) << 23);
            e2acc += (e - 127);
            sh_v[tid] = v * inv;
        }
        #pragma unroll
        for (int j = 0; j < 16; ++j) cur[j] = nxt[j];
        __syncthreads();
    }

    // score = ln2*(e2acc + sscal) + log(sum_d alpha[d])
    if (tid < SS) {
        float s = sh_v[tid];
        #pragma unroll
        for (int off = 32; off >= 1; off >>= 1)
            s += __shfl_xor(s, off, 64);
        if ((tid & 63) == 0) sh_red[tid >> 6] = s;
    }
    __syncthreads();
    if (tid == 0)
        dsc[u] = LN2F * ((float)e2acc + sscal) + __logf(sh_red[0] + sh_red[1]);
}

// ======================= Finalize ============================================
__global__ void mmi_finalize(const float* __restrict__ sc,
                             const int* __restrict__ sup,
                             float* __restrict__ out)
{
    const int tid = threadIdx.x;
    float tot_score = 0.0f, tot_frames = 0.0f, all_frames = 0.0f;
    if (tid < NB) {
        const float tot = sc[NB + tid] - sc[tid];
        const int nf = sup[tid * 3 + 2];
        const bool fin = isfinite(tot) && (tot > 0.5f * NEGV);
        tot_score  = fin ? tot : 0.0f;
        tot_frames = fin ? (float)nf : 0.0f;
        all_frames = (float)nf;
    }
    #pragma unroll
    for (int off = 32; off >= 1; off >>= 1) {
        tot_score  += __shfl_xor(tot_score, off, 64);
        tot_frames += __shfl_xor(tot_frames, off, 64);
        all_frames += __shfl_xor(all_frames, off, 64);
    }
    if (tid == 0) {
        out[0] = tot_score;
        out[1] = tot_frames;
        out[2] = all_frames;
    }
}

// ======================= Fallback (validated round-4 kernel) =================
#define XBF (16 * FF)
__global__ __launch_bounds__(256) void mmi_forward_fb(
    const float* __restrict__ x, const int* __restrict__ sup,
    const float* __restrict__ trans, const int* __restrict__ den_labels,
    const int* __restrict__ num_labels, const int* __restrict__ num_lens,
    float* __restrict__ ws)
{
    const int tid = threadIdx.x;
    if (blockIdx.x < NB) {
        __shared__ float sh_v[SS];
        __shared__ float sh_part[8 * SS];
        __shared__ float sh_red[4];
        __shared__ __align__(16) float xbuf[2][XBF];
        const int n = blockIdx.x, nf = sup[n * 3 + 2];
        const int g = tid & 31, c = tid >> 5;
        float4 e[16];
        #pragma unroll
        for (int j = 0; j < 16; ++j) {
            const float4 t4 = *(const float4*)(trans + (size_t)(16 * c + j) * SS + 4 * g);
            e[j] = make_float4(__expf(t4.x), __expf(t4.y), __expf(t4.z), __expf(t4.w));
        }
        const int lab = (tid < SS) ? den_labels[tid & (SS - 1)] : 0;
        const float* xb = x + (size_t)n * TT * FF;
        {
            const float4* s0 = (const float4*)xb;
            float4 p0 = s0[tid]; float4 p1; if (tid < 104) p1 = s0[256 + tid];
            float4* d0 = (float4*)xbuf[0];
            d0[tid] = p0; if (tid < 104) d0[256 + tid] = p1;
        }
        if (tid < SS) sh_v[tid] = (tid == 0) ? 1.0f : 0.0f;
        float logM = 0.0f, v = 0.0f, pe = 0.0f;
        float4 pf0, pf1;
        __syncthreads();
        for (int t = 0; t < nf; ++t) {
            const int b = t >> 4;
            if (tid < SS) pe = __expf(xbuf[b & 1][(t & 15) * FF + lab]);
            float4 aa[4];
            { const float4* av = (const float4*)(sh_v + 16 * c);
              aa[0] = av[0]; aa[1] = av[1]; aa[2] = av[2]; aa[3] = av[3]; }
            const float* as = (const float*)aa;
            float4 acc = make_float4(0.f, 0.f, 0.f, 0.f);
            #pragma unroll
            for (int j = 0; j < 16; ++j) {
                acc.x = fmaf(as[j], e[j].x, acc.x); acc.y = fmaf(as[j], e[j].y, acc.y);
                acc.z = fmaf(as[j], e[j].z, acc.z); acc.w = fmaf(as[j], e[j].w, acc.w);
            }
            *(float4*)(sh_part + c * SS + 4 * g) = acc;
            if ((t & 15) == 8) {
                const int tn = (b + 1) * 16;
                if (tn < nf) {
                    const float4* s = (const float4*)(xb + (size_t)tn * FF);
                    pf0 = s[tid]; if (tid < 104) pf1 = s[256 + tid];
                }
            }
            __syncthreads();
            const bool rs = ((t & 15) == 15);
            if (tid < SS) {
                float y = 0.0f;
                #pragma unroll
                for (int cc = 0; cc < 8; ++cc) y += sh_part[cc * SS + tid];
                v = y * pe;
                if (rs) {
                    float m = v;
                    #pragma unroll
                    for (int off = 32; off >= 1; off >>= 1)
                        m = fmaxf(m, __shfl_xor(m, off, 64));
                    if ((tid & 63) == 0) sh_red[tid >> 6] = m;
                }
            }
            if (rs) {
                const int tn = (b + 1) * 16;
                if (tn < nf) {
                    float4* dst = (float4*)xbuf[(b + 1) & 1];
                    dst[tid] = pf0; if (tid < 104) dst[256 + tid] = pf1;
                }
                __syncthreads();
                if (tid < SS) {
                    float mm = fmaxf(fmaxf(sh_red[0], sh_red[1]), 1e-37f);
                    v *= (1.0f / mm); logM += __logf(mm);
                }
            }
            if (tid < SS) sh_v[tid] = v;
            __syncthreads();
        }
        if (tid < SS) {
            float ssum = v;
            #pragma unroll
            for (int off = 32; off >= 1; off >>= 1) ssum += __shfl_xor(ssum, off, 64);
            if ((tid & 63) == 0) sh_red[2 + (tid >> 6)] = ssum;
        }
        __syncthreads();
        if (tid == 0) ws[n] = logM + __logf(sh_red[2] + sh_red[3]);
    } else {
        const int w = tid >> 6, l = tid & 63;
        const int n = (blockIdx.x - NB) * 4 + w;
        const int nf = sup[n * 3 + 2];
        const float* xb = x + (size_t)n * TT * FF;
        const int* nl = num_labels + n * LL;
        int li[4];
        #pragma unroll
        for (int k = 0; k < 4; ++k) li[k] = nl[min(4 * l + k, LL - 1)];
        float a4[4] = {NEGV, NEGV, NEGV, NEGV};
        float ea[4], eb[4];
        #pragma unroll
        for (int k = 0; k < 4; ++k) ea[k] = xb[li[k]];
        { const float* xr = xb + (size_t)min(1, nf - 1) * FF;
          #pragma unroll
          for (int k = 0; k < 4; ++k) eb[k] = xr[li[k]]; }
        auto step = [&](float (&ee)[4], int t) {
            float left = __shfl_up(a4[3], 1, 64);
            if (l == 0) left = (t == 0) ? 0.0f : NEGV;
            float prev = left;
            #pragma unroll
            for (int k = 0; k < 4; ++k) {
                const float a = a4[k], b = prev;
                const float mx = fmaxf(a, b), mn = fminf(a, b);
                const float nv = mx + __logf(1.0f + __expf(mn - mx)) + ee[k];
                prev = a4[k]; a4[k] = nv;
            }
            const int t2 = min(t + 2, nf - 1);
            const float* xr = xb + (size_t)t2 * FF;
            #pragma unroll
            for (int k = 0; k < 4; ++k) ee[k] = xr[li[k]];
        };
        int t = 0;
        while (t < nf) { step(ea, t); ++t; if (t >= nf) break; step(eb, t); ++t; }
        const int idx = num_lens[n] - 1;
        if ((idx >> 2) == l) {
            const int kk = idx & 3;
            float vv = (kk == 0) ? a4[0] : (kk == 1) ? a4[1] : (kk == 2) ? a4[2] : a4[3];
            ws[NB + n] = vv;
        }
    }
}

extern "C" void kernel_launch(void* const* d_in, const int* in_sizes, int n_in,
                              void* d_out, int out_size, void* d_ws, size_t ws_size,
                              hipStream_t stream) {
    const float* x          = (const float*)d_in[0];
    const int*   sup        = (const int*)d_in[1];
    const float* trans      = (const float*)d_in[2];
    const int*   den_labels = (const int*)d_in[3];
    const int*   num_labels = (const int*)d_in[4];
    const int*   num_lens   = (const int*)d_in[5];
    float* out = (float*)d_out;

    const size_t PBYTES = (size_t)NB * NODES * 128 * 128 * 2;   // 13,107,200
    const size_t NEEDED = PBYTES + (NB * NODES + 64) * sizeof(float);

    if (ws_size >= NEEDED) {
        unsigned* Pout  = (unsigned*)d_ws;
        float* scales   = (float*)((char*)d_ws + PBYTES);
        float* scores   = scales + NB * NODES;   // [0..15] den, [16..31] num
        mmi_nodes<<<dim3(NB * NODES + 4), dim3(256), 0, stream>>>(
            x, sup, trans, den_labels, num_labels, num_lens,
            Pout, scales, scores + NB);
        mmi_chain<<<dim3(NB), dim3(256), 0, stream>>>(
            (const unsigned short*)d_ws, scales, scores);
        mmi_finalize<<<dim3(1), dim3(64), 0, stream>>>(scores, sup, out);
    } else {
        float* ws = (float*)d_ws;
        mmi_forward_fb<<<dim3(20), dim3(256), 0, stream>>>(
            x, sup, trans, den_labels, num_labels, num_lens, ws);
        mmi_finalize<<<dim3(1), dim3(64), 0, stream>>>(ws, sup, out);
    }
}